// Round 15
// baseline (137.790 us; speedup 1.0000x reference)
//
#include <hip/hip_runtime.h>
#include <math.h>

#define T_DIM 2048
#define C_DIM 1024
#define H_DIM 64
#define M_TOTAL 16384            // B*T
#define NQKV 192                 // k(0..63) | q(64..127) | v(128..191)
#define VTS 2176                 // vT row stride: 64 pad | 2048 | 64 pad

typedef __bf16 bf16x8 __attribute__((ext_vector_type(8)));
typedef float f32x4 __attribute__((ext_vector_type(4)));
typedef float f32x2 __attribute__((ext_vector_type(2)));
typedef unsigned short u16x8 __attribute__((ext_vector_type(8)));

#if __has_builtin(__builtin_amdgcn_fdot2_f32_bf16)
#define HAVE_DOT2 1
typedef __bf16 bf16x2 __attribute__((ext_vector_type(2)));
#else
#define HAVE_DOT2 0
#endif

#if __has_builtin(__builtin_amdgcn_global_load_lds)
#define HAVE_GLL 1
__device__ __forceinline__ void gload_lds16(const unsigned short* g, unsigned short* l) {
    __builtin_amdgcn_global_load_lds(
        (const __attribute__((address_space(1))) unsigned int*)(const void*)g,
        (__attribute__((address_space(3))) unsigned int*)(void*)l,
        16, 0, 0);
}
#else
#define HAVE_GLL 0
#endif

__device__ __forceinline__ unsigned short f2bf(float f) {
    unsigned u = __float_as_uint(f);
    unsigned r = (u + 0x7FFFu + ((u >> 16) & 1u)) >> 16;   // RNE
    return (unsigned short)r;
}
__device__ __forceinline__ float bf2f(unsigned short u) {
    return __uint_as_float(((unsigned)u) << 16);
}
__device__ __forceinline__ float blo(unsigned u) { return __uint_as_float(u << 16); }
__device__ __forceinline__ float bhi(unsigned u) { return __uint_as_float(u & 0xFFFF0000u); }
__device__ __forceinline__ unsigned pack_bf2(float f0, float f1) {
    unsigned u0 = __float_as_uint(f0) + 0x8000u;
    unsigned u1 = __float_as_uint(f1) + 0x8000u;
    return __builtin_amdgcn_perm(u1, u0, 0x07060302u);
}
__device__ __forceinline__ uint4 cvt8(float4 a, float4 b) {
    return make_uint4(pack_bf2(a.x, a.y), pack_bf2(a.z, a.w),
                      pack_bf2(b.x, b.y), pack_bf2(b.z, b.w));
}

// 8-elem bf16 dot: v_dot2_f32_bf16 when available, fma fallback.
__device__ __forceinline__ float dot8bf(u16x8 a, u16x8 b, float c) {
#if HAVE_DOT2
    bf16x8 av = __builtin_bit_cast(bf16x8, a);
    bf16x8 bv = __builtin_bit_cast(bf16x8, b);
    #pragma unroll
    for (int e = 0; e < 4; ++e) {
        bf16x2 ap = {av[2 * e], av[2 * e + 1]};
        bf16x2 bp = {bv[2 * e], bv[2 * e + 1]};
        c = __builtin_amdgcn_fdot2_f32_bf16(ap, bp, c, false);
    }
#else
    #pragma unroll
    for (int e = 0; e < 8; ++e) c = fmaf(bf2f(a[e]), bf2f(b[e]), c);
#endif
    return c;
}

// ---------------------------------------------------------------------------
// DPP cross-lane (VALU pipe). 0xB1=xor1, 0x4E=xor2, 0x141=row_half_mirror
// (==xor4 on 4-uniform data), 0x140=row_mirror (==xor8 on 8-uniform data).
// Validated end-to-end by R10/R12-R22 passing runs.
// ---------------------------------------------------------------------------
#if __has_builtin(__builtin_amdgcn_update_dpp)
#define HAVE_DPP 1
template<int CTRL>
__device__ __forceinline__ float dppf(float x) {
    int v = __builtin_amdgcn_update_dpp(0, __builtin_bit_cast(int, x),
                                        CTRL, 0xF, 0xF, true);
    return __builtin_bit_cast(float, v);
}
__device__ __forceinline__ float red8(float p) {          // sum over 8-lane group
    p += dppf<0xB1>(p);
    p += dppf<0x4E>(p);
    p += dppf<0x141>(p);
    return p;
}
__device__ __forceinline__ float redsum16(float p) {      // sum over 16-lane row
    p += dppf<0xB1>(p);
    p += dppf<0x4E>(p);
    p += dppf<0x141>(p);
    p += dppf<0x140>(p);
    return p;
}
__device__ __forceinline__ float redmax16(float p) {
    p = fmaxf(p, dppf<0xB1>(p));
    p = fmaxf(p, dppf<0x4E>(p));
    p = fmaxf(p, dppf<0x141>(p));
    p = fmaxf(p, dppf<0x140>(p));
    return p;
}
__device__ __forceinline__ float xor8sum(float p) {       // requires 8-uniform
    return p + dppf<0x140>(p);
}
__device__ __forceinline__ float xor8max(float p) {       // requires 8-uniform
    return fmaxf(p, dppf<0x140>(p));
}
#else
#define HAVE_DPP 0
__device__ __forceinline__ float red8(float p) {
    p += __shfl_xor(p, 1); p += __shfl_xor(p, 2); p += __shfl_xor(p, 4);
    return p;
}
__device__ __forceinline__ float redsum16(float p) {
    p += __shfl_xor(p, 1); p += __shfl_xor(p, 2);
    p += __shfl_xor(p, 4); p += __shfl_xor(p, 8);
    return p;
}
__device__ __forceinline__ float redmax16(float p) {
    p = fmaxf(p, __shfl_xor(p, 1)); p = fmaxf(p, __shfl_xor(p, 2));
    p = fmaxf(p, __shfl_xor(p, 4)); p = fmaxf(p, __shfl_xor(p, 8));
    return p;
}
__device__ __forceinline__ float xor8sum(float p) { return p + __shfl_xor(p, 8); }
__device__ __forceinline__ float xor8max(float p) { return fmaxf(p, __shfl_xor(p, 8)); }
#endif

// ---------------------------------------------------------------------------
// Kernel P: merged prep (R19, validated) — blocks 0..511: random dedup +
// compaction; blocks 512..639: W fp32->bf16 pre-swizzled + vT pad zeroing.
// ---------------------------------------------------------------------------
__global__ __launch_bounds__(256) void prep_kernel(
    const float* __restrict__ Wk,
    const float* __restrict__ Wq,
    const float* __restrict__ Wv,
    const int*  __restrict__ rnd,         // [2048][64]
    unsigned short* __restrict__ wbf,     // [192][1024] bf16 bits
    unsigned short* __restrict__ vTz,     // [8*64][VTS]
    int* __restrict__ rjc,                // [2048][64]
    int* __restrict__ nvalb)              // [2048]
{
    if (blockIdx.x < 512) {
        __shared__ unsigned bm_all[4][64];
        const int wv = threadIdx.x >> 6;
        const int ln = threadIdx.x & 63;
        const int i  = blockIdx.x * 4 + wv;
        unsigned* bm = bm_all[wv];

        bm[ln] = 0u;
        int  j2 = rnd[i * 64 + ln];
        bool v2 = (j2 < i - 63) && (j2 >= 64);
        if (v2) {
            unsigned old = atomicOr(&bm[j2 >> 5], 1u << (j2 & 31));
            v2 = ((old >> (j2 & 31)) & 1u) == 0u;
        }
        unsigned long long mbal = __ballot(v2);
        const int nval = __popcll(mbal);
        if (v2) {
            int pos = __popcll(mbal & ((1ull << ln) - 1ull));
            rjc[i * 64 + pos] = j2;
        }
        if (ln >= nval) rjc[i * 64 + ln] = 0;   // safe pad
        if (ln == 0) nvalb[i] = nval;
    } else {
        int t = (blockIdx.x - 512) * 256 + threadIdx.x;   // 0..32767
        if (t < 24576) {
            int g8  = t & 7;
            int kc  = (t >> 3) & 15;
            int row = t >> 7;                             // 0..191
            const float* src = (row < 64)  ? Wk + (size_t)row * C_DIM
                             : (row < 128) ? Wq + (size_t)(row - 64) * C_DIM
                                           : Wv + (size_t)(row - 128) * C_DIM;
            int ksrc = kc * 64 + ((g8 * 8) ^ ((row & 7) * 8));
            float4 a = *(const float4*)(src + ksrc);
            float4 b = *(const float4*)(src + ksrc + 4);
            *(uint4*)(wbf + (size_t)row * C_DIM + kc * 64 + g8 * 8) = cvt8(a, b);
        } else {
            int t2    = t - 24576;                        // 0..8191
            int rowid = t2 >> 4;                          // 0..511 = b*64+h
            int sub   = t2 & 15;
            int off   = (sub < 8) ? sub * 8 : 2112 + (sub - 8) * 8;
            uint4 z = make_uint4(0u, 0u, 0u, 0u);
            *(uint4*)(vTz + (size_t)rowid * VTS + off) = z;
        }
    }
}

// ---------------------------------------------------------------------------
// Kernel 1: QKV projection — R21 (validated, best): R19 structure +
// depth-2 x prefetch. Unchanged.
// ---------------------------------------------------------------------------
__global__ __launch_bounds__(256) void proj_kernel(
    const float* __restrict__ x,
    const unsigned short* __restrict__ wbf,   // [192][1024] bf16 pre-swizzled
    unsigned short* __restrict__ qkv,         // [16384][192] bf16 bits
    unsigned short* __restrict__ vT)          // [8*64][VTS]
{
    __shared__ unsigned short Ab[32 * 64];    //  4 KB [row][k^swz]
    __shared__ unsigned short Bb[192 * 64];   // 24 KB [col][k^swz]
    __shared__ unsigned short vst[64 * 40];   //  5 KB [h][t] transpose buffer

    const int m0 = blockIdx.x * 32;
    const int t  = threadIdx.x;
    const int wv = t >> 6, ln = t & 63;       // 4 waves
    const int mfr = ln & 15, kq = ln >> 4;
    const int c0 = wv * 48;

    const int srow  = t >> 3;                 // 0..31
    const int sk8   = (t & 7) * 8;
    const int skoff = sk8 ^ ((srow & 7) * 8);

    const float* gpx = x + (size_t)(m0 + srow) * C_DIM + sk8;
    unsigned short* lpx = &Ab[srow * 64 + skoff];

    const int wrow = wv * 8 + (ln >> 3);      // 0..31
    const unsigned short* wsrc = wbf + (size_t)wrow * C_DIM + (ln & 7) * 8;

    f32x4 acc[2][3] = {};

    float4 ra  = *(const float4*)(gpx);
    float4 rb  = *(const float4*)(gpx + 4);
    float4 ra2 = *(const float4*)(gpx + 64);
    float4 rb2 = *(const float4*)(gpx + 68);

    for (int kc = 0; kc < C_DIM; kc += 64) {
        __syncthreads();
        *(uint4*)lpx = cvt8(ra, rb);
#if HAVE_GLL
        #pragma unroll
        for (int s = 0; s < 6; ++s)
            gload_lds16(wsrc + (size_t)s * 32 * C_DIM + kc,
                        &Bb[(s * 32 + wv * 8) * 64]);
#else
        #pragma unroll
        for (int s = 0; s < 6; ++s) {
            uint4 w4 = *(const uint4*)(wsrc + (size_t)s * 32 * C_DIM + kc);
            *(uint4*)&Bb[(s * 32 + wv * 8 + (ln >> 3)) * 64 + (ln & 7) * 8] = w4;
        }
#endif
        ra = ra2; rb = rb2;
        if (kc + 128 < C_DIM) {
            ra2 = *(const float4*)(gpx + kc + 128);
            rb2 = *(const float4*)(gpx + kc + 132);
        }
        __syncthreads();   // drains lgkm + vmcnt -> Ab/Bb ready
        #pragma unroll
        for (int ks = 0; ks < 64; ks += 32) {
            bf16x8 af[2], bf[3];
            #pragma unroll
            for (int a = 0; a < 2; ++a) {
                int row = a * 16 + mfr;
                af[a] = *(const bf16x8*)&Ab[row * 64 + ((ks + kq * 8) ^ ((row & 7) * 8))];
            }
            #pragma unroll
            for (int b2 = 0; b2 < 3; ++b2) {
                int row = c0 + b2 * 16 + mfr;
                bf[b2] = *(const bf16x8*)&Bb[row * 64 + ((ks + kq * 8) ^ ((row & 7) * 8))];
            }
            #pragma unroll
            for (int a = 0; a < 2; ++a)
                #pragma unroll
                for (int b2 = 0; b2 < 3; ++b2)
                    acc[a][b2] = __builtin_amdgcn_mfma_f32_16x16x32_bf16(
                        af[a], bf[b2], acc[a][b2], 0, 0, 0);
        }
    }

    #pragma unroll
    for (int a = 0; a < 2; ++a)
        #pragma unroll
        for (int b2 = 0; b2 < 3; ++b2)
            #pragma unroll
            for (int r = 0; r < 4; ++r) {
                int row = m0 + a * 16 + kq * 4 + r;
                int col = c0 + b2 * 16 + mfr;
                qkv[(size_t)row * NQKV + col] = f2bf(acc[a][b2][r]);
            }

    // ---- vT emit: V cols 128..191 -> vst[h][t] ----
    if (wv == 2) {
        #pragma unroll
        for (int a = 0; a < 2; ++a)
            #pragma unroll
            for (int r = 0; r < 4; ++r)
                vst[mfr * 40 + a * 16 + kq * 4 + r] = f2bf(acc[a][2][r]);
    } else if (wv == 3) {
        #pragma unroll
        for (int b2 = 0; b2 < 3; ++b2)
            #pragma unroll
            for (int a = 0; a < 2; ++a)
                #pragma unroll
                for (int r = 0; r < 4; ++r)
                    vst[(16 + b2 * 16 + mfr) * 40 + a * 16 + kq * 4 + r]
                        = f2bf(acc[a][b2][r]);
    }
    __syncthreads();
    {
        int h  = t >> 2;                 // 0..63
        int ch = t & 3;                  // 4 chunks of 8 -> 32 t
        uint4 vv = *(const uint4*)&vst[h * 40 + ch * 8];
        size_t bb = (size_t)(m0 >> 11);
        int    tt = m0 & 2047;
        *(uint4*)(vT + (bb * 64 + h) * VTS + 64 + tt + ch * 8) = vv;
    }
}

// ---------------------------------------------------------------------------
// Kernel 2: sparse BigBird attention — R23: R22 structure (validated,
// 135.6 µs) with LPT block ordering: i0 = (127 - (blockIdx>>3)) << 4.
// Per-block rand work grows linearly with i0 (nval ~ i0/32); ascending
// dispatch put the heaviest blocks in the LAST scheduling generation
// (longest-job-last tail). Reversing the i0 map schedules heavy blocks
// first so light ones backfill the tail. Pure index remap: work set,
// traffic, and numerics bit-identical. XCD swizzle (b = blockIdx&7)
// unchanged. All else byte-identical to R22.
// ---------------------------------------------------------------------------
__global__ __launch_bounds__(1024) void attn_kernel(
    const unsigned short* __restrict__ qkv,   // bf16 bits [16384][192]
    const unsigned short* __restrict__ vT,    // [8*64][VTS], col offset +64
    const int*  __restrict__ rjc,             // [2048][64]
    const int*  __restrict__ nvalb,           // [2048]
    float* __restrict__ out)                  // [16384][64]
{
    __shared__ unsigned short Qst[16 * 72];   //  2,304 B
    __shared__ float          sc [16 * 162];  // 10,368 B
    __shared__ unsigned short pw [16 * 168];  //  5,376 B
    __shared__ float          outR[16 * 72];  //  4,608 B
    __shared__ float          invs[16];

    const int tid = threadIdx.x;
    const int wv = tid >> 6;                        // 0..15 = q
    const int ln = tid & 63;
    const int b  = blockIdx.x & 7;                  // XCD swizzle
    const int i0 = (127 - (blockIdx.x >> 3)) << 4;  // LPT: heavy blocks first
    const int i  = i0 + wv;
    const int bi = b * T_DIM + i;

    const unsigned short* kb  = qkv + (size_t)b * T_DIM * NQKV;
    const unsigned short* vb  = kb + 128;
    const unsigned short* vTb = vT + (size_t)b * 64 * VTS + 64;

    const int e8  = (ln & 7) * 8;
    const int gg  = ln >> 3;
    const int m15 = ln & 15, kq4 = ln >> 4;
    const int q   = wv;

    // ---- early: rand meta + own q row ----
    const int  nval = nvalb[i];                     // wave-uniform
    const int* rji  = rjc + i * 64;
    int rj8[8];
    #pragma unroll
    for (int u = 0; u < 8; ++u) rj8[u] = rji[u * 8 + gg];
    u16x8 qraw = *(const u16x8*)(qkv + (size_t)bi * NQKV + 64 + e8);

    if (ln < 8) *(uint4*)&Qst[wv * 72 + ln * 8] = __builtin_bit_cast(uint4, qraw);
    __syncthreads();

    // ---- rand QK: four guarded 16-slot batches (2 slots/lane-group) ----
    float prs[8];
    #pragma unroll
    for (int u = 0; u < 8; ++u) prs[u] = 0.f;
    #pragma unroll
    for (int k = 0; k < 4; ++k) {
        if (nval > k * 16) {
            u16x8 kr[2];
            #pragma unroll
            for (int u = 0; u < 2; ++u)
                kr[u] = *(const u16x8*)(kb + (size_t)rj8[2 * k + u] * NQKV + e8);
            #pragma unroll
            for (int u = 0; u < 2; ++u)
                prs[2 * k + u] = red8(dot8bf(kr[u], qraw, 0.f));
        }
    }

    // ---- fixed QK via MFMA (waves 0..8; tile u = wv*16 .. +15) ----
    if (wv < 9) {
        int u   = wv * 16 + m15;
        int col = (u < 64) ? u : max(i0 + u - 128, 0);
        const unsigned short* kcol = kb + (size_t)col * NQKV;
        f32x4 c4 = {0.f, 0.f, 0.f, 0.f};
        #pragma unroll
        for (int ks = 0; ks < 64; ks += 32) {
            bf16x8 af = *(const bf16x8*)&Qst[m15 * 72 + ks + kq4 * 8];
            bf16x8 bf = *(const bf16x8*)(kcol + ks + kq4 * 8);
            c4 = __builtin_amdgcn_mfma_f32_16x16x32_bf16(af, bf, c4, 0, 0, 0);
        }
        #pragma unroll
        for (int r = 0; r < 4; ++r)
            sc[(kq4 * 4 + r) * 162 + u] = c4[r];
    }
    __syncthreads();

    // ---- softmax (wave q over its sc row + rand regs) ----
    const float* scq = sc + wv * 162;
    float s0 = scq[ln];
    float s1 = scq[64 + ln];
    float s2 = (ln < 16) ? scq[128 + ln] : 0.f;
    bool v0 = (ln < i - 63);
    bool v1 = (ln >= q + 1) && (i0 + ln - 64 >= 0);
    bool v2 = (ln <= q);
    s0 = v0 ? s0 * 0.125f : -1e30f;
    s1 = v1 ? s1 * 0.125f : -1e30f;
    s2 = v2 ? s2 * 0.125f : -1e30f;
    #pragma unroll
    for (int j = 0; j < 8; ++j) {
        bool vj = (j * 8 + gg) < nval;
        prs[j] = vj ? prs[j] * 0.125f : -1e30f;
    }

    float mf = fmaxf(s0, fmaxf(s1, s2));
    mf = redmax16(mf);
    mf = fmaxf(mf, __shfl_xor(mf, 16));
    mf = fmaxf(mf, __shfl_xor(mf, 32));
    float mr = prs[0];
    #pragma unroll
    for (int j = 1; j < 8; ++j) mr = fmaxf(mr, prs[j]);
    mr = xor8max(mr);
    mr = fmaxf(mr, __shfl_xor(mr, 16));
    mr = fmaxf(mr, __shfl_xor(mr, 32));
    float mx = fmaxf(mf, mr);

    float e0 = v0 ? __expf(s0 - mx) : 0.f;
    float e1 = v1 ? __expf(s1 - mx) : 0.f;
    float e2 = v2 ? __expf(s2 - mx) : 0.f;
    float sumf = e0 + e1 + e2;
    sumf = redsum16(sumf);
    sumf += __shfl_xor(sumf, 16);
    sumf += __shfl_xor(sumf, 32);
    float er[8], sumr = 0.f;
    #pragma unroll
    for (int j = 0; j < 8; ++j) {
        er[j] = __expf(prs[j] - mx);
        sumr += er[j];
    }
    sumr = xor8sum(sumr);
    sumr += __shfl_xor(sumr, 16);
    sumr += __shfl_xor(sumr, 32);
    float sum = sumf + sumr;

    unsigned short* pwq = pw + wv * 168;
    pwq[ln]      = f2bf(e0);
    pwq[64 + ln] = f2bf(e1);
    if (ln < 32) pwq[128 + ln] = (ln < 16) ? f2bf(e2) : (unsigned short)0;

    // ---- rand PV: four guarded 16-slot batches -> outR ----
    f32x2 acc2[4] = {};
    #pragma unroll
    for (int k = 0; k < 4; ++k) {
        if (nval > k * 16) {
            uint4 vr[2];
            #pragma unroll
            for (int u = 0; u < 2; ++u)
                vr[u] = *(const uint4*)(vb + (size_t)rj8[2 * k + u] * NQKV + e8);
            #pragma unroll
            for (int u = 0; u < 2; ++u) {
                float w = er[2 * k + u];
                f32x2 w2 = {w, w};
                f32x2 p0 = {blo(vr[u].x), bhi(vr[u].x)};
                f32x2 p1 = {blo(vr[u].y), bhi(vr[u].y)};
                f32x2 p2 = {blo(vr[u].z), bhi(vr[u].z)};
                f32x2 p3 = {blo(vr[u].w), bhi(vr[u].w)};
                acc2[0] += w2 * p0;
                acc2[1] += w2 * p1;
                acc2[2] += w2 * p2;
                acc2[3] += w2 * p3;
            }
        }
    }
    float acc[8] = { acc2[0][0], acc2[0][1], acc2[1][0], acc2[1][1],
                     acc2[2][0], acc2[2][1], acc2[3][0], acc2[3][1] };
    #pragma unroll
    for (int m = 8; m <= 32; m <<= 1)
        #pragma unroll
        for (int e = 0; e < 8; ++e)
            acc[e] += __shfl_xor(acc[e], m);
    if (ln < 8) {
        *(float4*)&outR[wv * 72 + ln * 8]     = make_float4(acc[0], acc[1], acc[2], acc[3]);
        *(float4*)&outR[wv * 72 + ln * 8 + 4] = make_float4(acc[4], acc[5], acc[6], acc[7]);
    }
    if (ln == 0) invs[wv] = 1.f / sum;
    __syncthreads();

    // ---- fixed PV via MFMA + epilogue (waves 0..3; h-tile = wv*16..+15) ----
    if (wv < 4) {
        const int h = wv * 16 + m15;
        const unsigned short* vrow = vTb + (size_t)h * VTS;
        f32x4 c4 = {0.f, 0.f, 0.f, 0.f};
        #pragma unroll
        for (int ks = 0; ks < 160; ks += 32) {
            int u0 = ks + kq4 * 8;
            int cb = (u0 < 64) ? u0 : (i0 + u0 - 128);
            bf16x8 bf = *(const bf16x8*)(vrow + cb);
            bf16x8 af = *(const bf16x8*)&pw[m15 * 168 + u0];
            c4 = __builtin_amdgcn_mfma_f32_16x16x32_bf16(af, bf, c4, 0, 0, 0);
        }
        #pragma unroll
        for (int r = 0; r < 4; ++r) {
            int qq = kq4 * 4 + r;
            float o = (c4[r] + outR[qq * 72 + h]) * invs[qq];
            out[((size_t)b * T_DIM + i0 + qq) * H_DIM + h] = o;
        }
    }
}

// ---------------------------------------------------------------------------
extern "C" void kernel_launch(void* const* d_in, const int* in_sizes, int n_in,
                              void* d_out, int out_size, void* d_ws, size_t ws_size,
                              hipStream_t stream) {
    const float* x   = (const float*)d_in[0];
    const int*   rnd = (const int*)  d_in[1];
    const float* Wk  = (const float*)d_in[2];
    const float* Wq  = (const float*)d_in[3];
    const float* Wv  = (const float*)d_in[4];
    float* out = (float*)d_out;

    unsigned short* qkv = (unsigned short*)d_ws;                     // 6,291,456 B
    int* rjc   = (int*)((char*)d_ws + 6291456);                      //   524,288 B
    int* nvalb = rjc + T_DIM * 64;                                   //     8,192 B
    unsigned short* wbf = (unsigned short*)((char*)d_ws + 6823936);  //   393,216 B
    unsigned short* vT  = (unsigned short*)((char*)d_ws + 7217152);  // 2,228,224 B

    prep_kernel<<<640, 256, 0, stream>>>(Wk, Wq, Wv, rnd, wbf, vT, rjc, nvalb);
    proj_kernel<<<M_TOTAL / 32, 256, 0, stream>>>(x, wbf, qkv, vT);
    attn_kernel<<<M_TOTAL / 16, 1024, 0, stream>>>(qkv, vT, rjc, nvalb, out);
}

// Round 16
// 133.526 us; speedup vs baseline: 1.0319x; 1.0319x over previous
//
#include <hip/hip_runtime.h>
#include <math.h>

#define T_DIM 2048
#define C_DIM 1024
#define H_DIM 64
#define M_TOTAL 16384            // B*T
#define NQKV 192                 // k(0..63) | q(64..127) | v(128..191)
#define VTS 2176                 // vT row stride: 64 pad | 2048 | 64 pad

typedef __bf16 bf16x8 __attribute__((ext_vector_type(8)));
typedef float f32x4 __attribute__((ext_vector_type(4)));
typedef float f32x2 __attribute__((ext_vector_type(2)));
typedef unsigned short u16x8 __attribute__((ext_vector_type(8)));

#if __has_builtin(__builtin_amdgcn_fdot2_f32_bf16)
#define HAVE_DOT2 1
typedef __bf16 bf16x2 __attribute__((ext_vector_type(2)));
#else
#define HAVE_DOT2 0
#endif

#if __has_builtin(__builtin_amdgcn_global_load_lds)
#define HAVE_GLL 1
__device__ __forceinline__ void gload_lds16(const unsigned short* g, unsigned short* l) {
    __builtin_amdgcn_global_load_lds(
        (const __attribute__((address_space(1))) unsigned int*)(const void*)g,
        (__attribute__((address_space(3))) unsigned int*)(void*)l,
        16, 0, 0);
}
#else
#define HAVE_GLL 0
#endif

__device__ __forceinline__ unsigned short f2bf(float f) {
    unsigned u = __float_as_uint(f);
    unsigned r = (u + 0x7FFFu + ((u >> 16) & 1u)) >> 16;   // RNE
    return (unsigned short)r;
}
__device__ __forceinline__ float bf2f(unsigned short u) {
    return __uint_as_float(((unsigned)u) << 16);
}
__device__ __forceinline__ float blo(unsigned u) { return __uint_as_float(u << 16); }
__device__ __forceinline__ float bhi(unsigned u) { return __uint_as_float(u & 0xFFFF0000u); }
__device__ __forceinline__ unsigned pack_bf2(float f0, float f1) {
    unsigned u0 = __float_as_uint(f0) + 0x8000u;
    unsigned u1 = __float_as_uint(f1) + 0x8000u;
    return __builtin_amdgcn_perm(u1, u0, 0x07060302u);
}
__device__ __forceinline__ uint4 cvt8(float4 a, float4 b) {
    return make_uint4(pack_bf2(a.x, a.y), pack_bf2(a.z, a.w),
                      pack_bf2(b.x, b.y), pack_bf2(b.z, b.w));
}

// 8-elem bf16 dot: v_dot2_f32_bf16 when available, fma fallback.
__device__ __forceinline__ float dot8bf(u16x8 a, u16x8 b, float c) {
#if HAVE_DOT2
    bf16x8 av = __builtin_bit_cast(bf16x8, a);
    bf16x8 bv = __builtin_bit_cast(bf16x8, b);
    #pragma unroll
    for (int e = 0; e < 4; ++e) {
        bf16x2 ap = {av[2 * e], av[2 * e + 1]};
        bf16x2 bp = {bv[2 * e], bv[2 * e + 1]};
        c = __builtin_amdgcn_fdot2_f32_bf16(ap, bp, c, false);
    }
#else
    #pragma unroll
    for (int e = 0; e < 8; ++e) c = fmaf(bf2f(a[e]), bf2f(b[e]), c);
#endif
    return c;
}

// ---------------------------------------------------------------------------
// DPP cross-lane (VALU pipe). 0xB1=xor1, 0x4E=xor2, 0x141=row_half_mirror
// (==xor4 on 4-uniform data), 0x140=row_mirror (==xor8 on 8-uniform data).
// Validated end-to-end by R10/R12-R22 passing runs.
// ---------------------------------------------------------------------------
#if __has_builtin(__builtin_amdgcn_update_dpp)
#define HAVE_DPP 1
template<int CTRL>
__device__ __forceinline__ float dppf(float x) {
    int v = __builtin_amdgcn_update_dpp(0, __builtin_bit_cast(int, x),
                                        CTRL, 0xF, 0xF, true);
    return __builtin_bit_cast(float, v);
}
__device__ __forceinline__ float red8(float p) {          // sum over 8-lane group
    p += dppf<0xB1>(p);
    p += dppf<0x4E>(p);
    p += dppf<0x141>(p);
    return p;
}
__device__ __forceinline__ float redsum16(float p) {      // sum over 16-lane row
    p += dppf<0xB1>(p);
    p += dppf<0x4E>(p);
    p += dppf<0x141>(p);
    p += dppf<0x140>(p);
    return p;
}
__device__ __forceinline__ float redmax16(float p) {
    p = fmaxf(p, dppf<0xB1>(p));
    p = fmaxf(p, dppf<0x4E>(p));
    p = fmaxf(p, dppf<0x141>(p));
    p = fmaxf(p, dppf<0x140>(p));
    return p;
}
__device__ __forceinline__ float xor8sum(float p) {       // requires 8-uniform
    return p + dppf<0x140>(p);
}
__device__ __forceinline__ float xor8max(float p) {       // requires 8-uniform
    return fmaxf(p, dppf<0x140>(p));
}
#else
#define HAVE_DPP 0
__device__ __forceinline__ float red8(float p) {
    p += __shfl_xor(p, 1); p += __shfl_xor(p, 2); p += __shfl_xor(p, 4);
    return p;
}
__device__ __forceinline__ float redsum16(float p) {
    p += __shfl_xor(p, 1); p += __shfl_xor(p, 2);
    p += __shfl_xor(p, 4); p += __shfl_xor(p, 8);
    return p;
}
__device__ __forceinline__ float redmax16(float p) {
    p = fmaxf(p, __shfl_xor(p, 1)); p = fmaxf(p, __shfl_xor(p, 2));
    p = fmaxf(p, __shfl_xor(p, 4)); p = fmaxf(p, __shfl_xor(p, 8));
    return p;
}
__device__ __forceinline__ float xor8sum(float p) { return p + __shfl_xor(p, 8); }
__device__ __forceinline__ float xor8max(float p) { return fmaxf(p, __shfl_xor(p, 8)); }
#endif

// ---------------------------------------------------------------------------
// Kernel P: merged prep (R19, validated) — blocks 0..511: random dedup +
// compaction; blocks 512..639: W fp32->bf16 pre-swizzled + vT pad zeroing.
// ---------------------------------------------------------------------------
__global__ __launch_bounds__(256) void prep_kernel(
    const float* __restrict__ Wk,
    const float* __restrict__ Wq,
    const float* __restrict__ Wv,
    const int*  __restrict__ rnd,         // [2048][64]
    unsigned short* __restrict__ wbf,     // [192][1024] bf16 bits
    unsigned short* __restrict__ vTz,     // [8*64][VTS]
    int* __restrict__ rjc,                // [2048][64]
    int* __restrict__ nvalb)              // [2048]
{
    if (blockIdx.x < 512) {
        __shared__ unsigned bm_all[4][64];
        const int wv = threadIdx.x >> 6;
        const int ln = threadIdx.x & 63;
        const int i  = blockIdx.x * 4 + wv;
        unsigned* bm = bm_all[wv];

        bm[ln] = 0u;
        int  j2 = rnd[i * 64 + ln];
        bool v2 = (j2 < i - 63) && (j2 >= 64);
        if (v2) {
            unsigned old = atomicOr(&bm[j2 >> 5], 1u << (j2 & 31));
            v2 = ((old >> (j2 & 31)) & 1u) == 0u;
        }
        unsigned long long mbal = __ballot(v2);
        const int nval = __popcll(mbal);
        if (v2) {
            int pos = __popcll(mbal & ((1ull << ln) - 1ull));
            rjc[i * 64 + pos] = j2;
        }
        if (ln >= nval) rjc[i * 64 + ln] = 0;   // safe pad
        if (ln == 0) nvalb[i] = nval;
    } else {
        int t = (blockIdx.x - 512) * 256 + threadIdx.x;   // 0..32767
        if (t < 24576) {
            int g8  = t & 7;
            int kc  = (t >> 3) & 15;
            int row = t >> 7;                             // 0..191
            const float* src = (row < 64)  ? Wk + (size_t)row * C_DIM
                             : (row < 128) ? Wq + (size_t)(row - 64) * C_DIM
                                           : Wv + (size_t)(row - 128) * C_DIM;
            int ksrc = kc * 64 + ((g8 * 8) ^ ((row & 7) * 8));
            float4 a = *(const float4*)(src + ksrc);
            float4 b = *(const float4*)(src + ksrc + 4);
            *(uint4*)(wbf + (size_t)row * C_DIM + kc * 64 + g8 * 8) = cvt8(a, b);
        } else {
            int t2    = t - 24576;                        // 0..8191
            int rowid = t2 >> 4;                          // 0..511 = b*64+h
            int sub   = t2 & 15;
            int off   = (sub < 8) ? sub * 8 : 2112 + (sub - 8) * 8;
            uint4 z = make_uint4(0u, 0u, 0u, 0u);
            *(uint4*)(vTz + (size_t)rowid * VTS + off) = z;
        }
    }
}

// ---------------------------------------------------------------------------
// Kernel 1: QKV projection — R21 (validated, best): R19 structure +
// depth-2 x prefetch. Unchanged.
// ---------------------------------------------------------------------------
__global__ __launch_bounds__(256) void proj_kernel(
    const float* __restrict__ x,
    const unsigned short* __restrict__ wbf,   // [192][1024] bf16 pre-swizzled
    unsigned short* __restrict__ qkv,         // [16384][192] bf16 bits
    unsigned short* __restrict__ vT)          // [8*64][VTS]
{
    __shared__ unsigned short Ab[32 * 64];    //  4 KB [row][k^swz]
    __shared__ unsigned short Bb[192 * 64];   // 24 KB [col][k^swz]
    __shared__ unsigned short vst[64 * 40];   //  5 KB [h][t] transpose buffer

    const int m0 = blockIdx.x * 32;
    const int t  = threadIdx.x;
    const int wv = t >> 6, ln = t & 63;       // 4 waves
    const int mfr = ln & 15, kq = ln >> 4;
    const int c0 = wv * 48;

    const int srow  = t >> 3;                 // 0..31
    const int sk8   = (t & 7) * 8;
    const int skoff = sk8 ^ ((srow & 7) * 8);

    const float* gpx = x + (size_t)(m0 + srow) * C_DIM + sk8;
    unsigned short* lpx = &Ab[srow * 64 + skoff];

    const int wrow = wv * 8 + (ln >> 3);      // 0..31
    const unsigned short* wsrc = wbf + (size_t)wrow * C_DIM + (ln & 7) * 8;

    f32x4 acc[2][3] = {};

    float4 ra  = *(const float4*)(gpx);
    float4 rb  = *(const float4*)(gpx + 4);
    float4 ra2 = *(const float4*)(gpx + 64);
    float4 rb2 = *(const float4*)(gpx + 68);

    for (int kc = 0; kc < C_DIM; kc += 64) {
        __syncthreads();
        *(uint4*)lpx = cvt8(ra, rb);
#if HAVE_GLL
        #pragma unroll
        for (int s = 0; s < 6; ++s)
            gload_lds16(wsrc + (size_t)s * 32 * C_DIM + kc,
                        &Bb[(s * 32 + wv * 8) * 64]);
#else
        #pragma unroll
        for (int s = 0; s < 6; ++s) {
            uint4 w4 = *(const uint4*)(wsrc + (size_t)s * 32 * C_DIM + kc);
            *(uint4*)&Bb[(s * 32 + wv * 8 + (ln >> 3)) * 64 + (ln & 7) * 8] = w4;
        }
#endif
        ra = ra2; rb = rb2;
        if (kc + 128 < C_DIM) {
            ra2 = *(const float4*)(gpx + kc + 128);
            rb2 = *(const float4*)(gpx + kc + 132);
        }
        __syncthreads();   // drains lgkm + vmcnt -> Ab/Bb ready
        #pragma unroll
        for (int ks = 0; ks < 64; ks += 32) {
            bf16x8 af[2], bf[3];
            #pragma unroll
            for (int a = 0; a < 2; ++a) {
                int row = a * 16 + mfr;
                af[a] = *(const bf16x8*)&Ab[row * 64 + ((ks + kq * 8) ^ ((row & 7) * 8))];
            }
            #pragma unroll
            for (int b2 = 0; b2 < 3; ++b2) {
                int row = c0 + b2 * 16 + mfr;
                bf[b2] = *(const bf16x8*)&Bb[row * 64 + ((ks + kq * 8) ^ ((row & 7) * 8))];
            }
            #pragma unroll
            for (int a = 0; a < 2; ++a)
                #pragma unroll
                for (int b2 = 0; b2 < 3; ++b2)
                    acc[a][b2] = __builtin_amdgcn_mfma_f32_16x16x32_bf16(
                        af[a], bf[b2], acc[a][b2], 0, 0, 0);
        }
    }

    #pragma unroll
    for (int a = 0; a < 2; ++a)
        #pragma unroll
        for (int b2 = 0; b2 < 3; ++b2)
            #pragma unroll
            for (int r = 0; r < 4; ++r) {
                int row = m0 + a * 16 + kq * 4 + r;
                int col = c0 + b2 * 16 + mfr;
                qkv[(size_t)row * NQKV + col] = f2bf(acc[a][b2][r]);
            }

    // ---- vT emit: V cols 128..191 -> vst[h][t] ----
    if (wv == 2) {
        #pragma unroll
        for (int a = 0; a < 2; ++a)
            #pragma unroll
            for (int r = 0; r < 4; ++r)
                vst[mfr * 40 + a * 16 + kq * 4 + r] = f2bf(acc[a][2][r]);
    } else if (wv == 3) {
        #pragma unroll
        for (int b2 = 0; b2 < 3; ++b2)
            #pragma unroll
            for (int a = 0; a < 2; ++a)
                #pragma unroll
                for (int r = 0; r < 4; ++r)
                    vst[(16 + b2 * 16 + mfr) * 40 + a * 16 + kq * 4 + r]
                        = f2bf(acc[a][b2][r]);
    }
    __syncthreads();
    {
        int h  = t >> 2;                 // 0..63
        int ch = t & 3;                  // 4 chunks of 8 -> 32 t
        uint4 vv = *(const uint4*)&vst[h * 40 + ch * 8];
        size_t bb = (size_t)(m0 >> 11);
        int    tt = m0 & 2047;
        *(uint4*)(vT + (bb * 64 + h) * VTS + 64 + tt + ch * 8) = vv;
    }
}

// ---------------------------------------------------------------------------
// Kernel 2: sparse BigBird attention — R24 == R22 exactly (best validated,
// 135.6 µs). R23's LPT i0-reversal regressed ~2 µs (broke ascending-order
// L2 adjacency) and is reverted. Structure: Qst staging, 16-slot-guarded
// rand batches, MFMA fixed QK/PV, ascending i0, XCD swizzle.
// ---------------------------------------------------------------------------
__global__ __launch_bounds__(1024) void attn_kernel(
    const unsigned short* __restrict__ qkv,   // bf16 bits [16384][192]
    const unsigned short* __restrict__ vT,    // [8*64][VTS], col offset +64
    const int*  __restrict__ rjc,             // [2048][64]
    const int*  __restrict__ nvalb,           // [2048]
    float* __restrict__ out)                  // [16384][64]
{
    __shared__ unsigned short Qst[16 * 72];   //  2,304 B
    __shared__ float          sc [16 * 162];  // 10,368 B
    __shared__ unsigned short pw [16 * 168];  //  5,376 B
    __shared__ float          outR[16 * 72];  //  4,608 B
    __shared__ float          invs[16];

    const int tid = threadIdx.x;
    const int wv = tid >> 6;                        // 0..15 = q
    const int ln = tid & 63;
    const int b  = blockIdx.x & 7;                  // XCD swizzle
    const int i0 = (blockIdx.x >> 3) << 4;
    const int i  = i0 + wv;
    const int bi = b * T_DIM + i;

    const unsigned short* kb  = qkv + (size_t)b * T_DIM * NQKV;
    const unsigned short* vb  = kb + 128;
    const unsigned short* vTb = vT + (size_t)b * 64 * VTS + 64;

    const int e8  = (ln & 7) * 8;
    const int gg  = ln >> 3;
    const int m15 = ln & 15, kq4 = ln >> 4;
    const int q   = wv;

    // ---- early: rand meta + own q row ----
    const int  nval = nvalb[i];                     // wave-uniform
    const int* rji  = rjc + i * 64;
    int rj8[8];
    #pragma unroll
    for (int u = 0; u < 8; ++u) rj8[u] = rji[u * 8 + gg];
    u16x8 qraw = *(const u16x8*)(qkv + (size_t)bi * NQKV + 64 + e8);

    if (ln < 8) *(uint4*)&Qst[wv * 72 + ln * 8] = __builtin_bit_cast(uint4, qraw);
    __syncthreads();

    // ---- rand QK: four guarded 16-slot batches (2 slots/lane-group) ----
    float prs[8];
    #pragma unroll
    for (int u = 0; u < 8; ++u) prs[u] = 0.f;
    #pragma unroll
    for (int k = 0; k < 4; ++k) {
        if (nval > k * 16) {
            u16x8 kr[2];
            #pragma unroll
            for (int u = 0; u < 2; ++u)
                kr[u] = *(const u16x8*)(kb + (size_t)rj8[2 * k + u] * NQKV + e8);
            #pragma unroll
            for (int u = 0; u < 2; ++u)
                prs[2 * k + u] = red8(dot8bf(kr[u], qraw, 0.f));
        }
    }

    // ---- fixed QK via MFMA (waves 0..8; tile u = wv*16 .. +15) ----
    if (wv < 9) {
        int u   = wv * 16 + m15;
        int col = (u < 64) ? u : max(i0 + u - 128, 0);
        const unsigned short* kcol = kb + (size_t)col * NQKV;
        f32x4 c4 = {0.f, 0.f, 0.f, 0.f};
        #pragma unroll
        for (int ks = 0; ks < 64; ks += 32) {
            bf16x8 af = *(const bf16x8*)&Qst[m15 * 72 + ks + kq4 * 8];
            bf16x8 bf = *(const bf16x8*)(kcol + ks + kq4 * 8);
            c4 = __builtin_amdgcn_mfma_f32_16x16x32_bf16(af, bf, c4, 0, 0, 0);
        }
        #pragma unroll
        for (int r = 0; r < 4; ++r)
            sc[(kq4 * 4 + r) * 162 + u] = c4[r];
    }
    __syncthreads();

    // ---- softmax (wave q over its sc row + rand regs) ----
    const float* scq = sc + wv * 162;
    float s0 = scq[ln];
    float s1 = scq[64 + ln];
    float s2 = (ln < 16) ? scq[128 + ln] : 0.f;
    bool v0 = (ln < i - 63);
    bool v1 = (ln >= q + 1) && (i0 + ln - 64 >= 0);
    bool v2 = (ln <= q);
    s0 = v0 ? s0 * 0.125f : -1e30f;
    s1 = v1 ? s1 * 0.125f : -1e30f;
    s2 = v2 ? s2 * 0.125f : -1e30f;
    #pragma unroll
    for (int j = 0; j < 8; ++j) {
        bool vj = (j * 8 + gg) < nval;
        prs[j] = vj ? prs[j] * 0.125f : -1e30f;
    }

    float mf = fmaxf(s0, fmaxf(s1, s2));
    mf = redmax16(mf);
    mf = fmaxf(mf, __shfl_xor(mf, 16));
    mf = fmaxf(mf, __shfl_xor(mf, 32));
    float mr = prs[0];
    #pragma unroll
    for (int j = 1; j < 8; ++j) mr = fmaxf(mr, prs[j]);
    mr = xor8max(mr);
    mr = fmaxf(mr, __shfl_xor(mr, 16));
    mr = fmaxf(mr, __shfl_xor(mr, 32));
    float mx = fmaxf(mf, mr);

    float e0 = v0 ? __expf(s0 - mx) : 0.f;
    float e1 = v1 ? __expf(s1 - mx) : 0.f;
    float e2 = v2 ? __expf(s2 - mx) : 0.f;
    float sumf = e0 + e1 + e2;
    sumf = redsum16(sumf);
    sumf += __shfl_xor(sumf, 16);
    sumf += __shfl_xor(sumf, 32);
    float er[8], sumr = 0.f;
    #pragma unroll
    for (int j = 0; j < 8; ++j) {
        er[j] = __expf(prs[j] - mx);
        sumr += er[j];
    }
    sumr = xor8sum(sumr);
    sumr += __shfl_xor(sumr, 16);
    sumr += __shfl_xor(sumr, 32);
    float sum = sumf + sumr;

    unsigned short* pwq = pw + wv * 168;
    pwq[ln]      = f2bf(e0);
    pwq[64 + ln] = f2bf(e1);
    if (ln < 32) pwq[128 + ln] = (ln < 16) ? f2bf(e2) : (unsigned short)0;

    // ---- rand PV: four guarded 16-slot batches -> outR ----
    f32x2 acc2[4] = {};
    #pragma unroll
    for (int k = 0; k < 4; ++k) {
        if (nval > k * 16) {
            uint4 vr[2];
            #pragma unroll
            for (int u = 0; u < 2; ++u)
                vr[u] = *(const uint4*)(vb + (size_t)rj8[2 * k + u] * NQKV + e8);
            #pragma unroll
            for (int u = 0; u < 2; ++u) {
                float w = er[2 * k + u];
                f32x2 w2 = {w, w};
                f32x2 p0 = {blo(vr[u].x), bhi(vr[u].x)};
                f32x2 p1 = {blo(vr[u].y), bhi(vr[u].y)};
                f32x2 p2 = {blo(vr[u].z), bhi(vr[u].z)};
                f32x2 p3 = {blo(vr[u].w), bhi(vr[u].w)};
                acc2[0] += w2 * p0;
                acc2[1] += w2 * p1;
                acc2[2] += w2 * p2;
                acc2[3] += w2 * p3;
            }
        }
    }
    float acc[8] = { acc2[0][0], acc2[0][1], acc2[1][0], acc2[1][1],
                     acc2[2][0], acc2[2][1], acc2[3][0], acc2[3][1] };
    #pragma unroll
    for (int m = 8; m <= 32; m <<= 1)
        #pragma unroll
        for (int e = 0; e < 8; ++e)
            acc[e] += __shfl_xor(acc[e], m);
    if (ln < 8) {
        *(float4*)&outR[wv * 72 + ln * 8]     = make_float4(acc[0], acc[1], acc[2], acc[3]);
        *(float4*)&outR[wv * 72 + ln * 8 + 4] = make_float4(acc[4], acc[5], acc[6], acc[7]);
    }
    if (ln == 0) invs[wv] = 1.f / sum;
    __syncthreads();

    // ---- fixed PV via MFMA + epilogue (waves 0..3; h-tile = wv*16..+15) ----
    if (wv < 4) {
        const int h = wv * 16 + m15;
        const unsigned short* vrow = vTb + (size_t)h * VTS;
        f32x4 c4 = {0.f, 0.f, 0.f, 0.f};
        #pragma unroll
        for (int ks = 0; ks < 160; ks += 32) {
            int u0 = ks + kq4 * 8;
            int cb = (u0 < 64) ? u0 : (i0 + u0 - 128);
            bf16x8 bf = *(const bf16x8*)(vrow + cb);
            bf16x8 af = *(const bf16x8*)&pw[m15 * 168 + u0];
            c4 = __builtin_amdgcn_mfma_f32_16x16x32_bf16(af, bf, c4, 0, 0, 0);
        }
        #pragma unroll
        for (int r = 0; r < 4; ++r) {
            int qq = kq4 * 4 + r;
            float o = (c4[r] + outR[qq * 72 + h]) * invs[qq];
            out[((size_t)b * T_DIM + i0 + qq) * H_DIM + h] = o;
        }
    }
}

// ---------------------------------------------------------------------------
extern "C" void kernel_launch(void* const* d_in, const int* in_sizes, int n_in,
                              void* d_out, int out_size, void* d_ws, size_t ws_size,
                              hipStream_t stream) {
    const float* x   = (const float*)d_in[0];
    const int*   rnd = (const int*)  d_in[1];
    const float* Wk  = (const float*)d_in[2];
    const float* Wq  = (const float*)d_in[3];
    const float* Wv  = (const float*)d_in[4];
    float* out = (float*)d_out;

    unsigned short* qkv = (unsigned short*)d_ws;                     // 6,291,456 B
    int* rjc   = (int*)((char*)d_ws + 6291456);                      //   524,288 B
    int* nvalb = rjc + T_DIM * 64;                                   //     8,192 B
    unsigned short* wbf = (unsigned short*)((char*)d_ws + 6823936);  //   393,216 B
    unsigned short* vT  = (unsigned short*)((char*)d_ws + 7217152);  // 2,228,224 B

    prep_kernel<<<640, 256, 0, stream>>>(Wk, Wq, Wv, rnd, wbf, vT, rjc, nvalb);
    proj_kernel<<<M_TOTAL / 32, 256, 0, stream>>>(x, wbf, qkv, vT);
    attn_kernel<<<M_TOTAL / 16, 1024, 0, stream>>>(qkv, vT, rjc, nvalb, out);
}